// Round 2
// baseline (11808.068 us; speedup 1.0000x reference)
//
#include <hip/hip_runtime.h>
#include <hip/hip_fp16.h>

#define TCH 256
#define NCH 4

typedef __attribute__((ext_vector_type(8))) _Float16 half8;
typedef __attribute__((ext_vector_type(4))) float floatx4;

// ---------------- GEMM: C[m,n] = A[m,:] . B[n,:]  (B row-major [N][K], fp32)
// A is f16 (or fp32 for MLP1), staged to LDS as f16; MFMA 16x16x32 f16.
template<bool AF32, bool RELUB>
__global__ __launch_bounds__(256, 2) void gemm_k(
    const void* __restrict__ Ab, const float* __restrict__ Bw,
    const float* __restrict__ bias, __half* __restrict__ C,
    const int* __restrict__ length, int K, int KT, int N, int arst, int t0)
{
  int b = blockIdx.x >> 1;                  // 2 m-tiles (128 rows) per batch elem
  int tloc0 = (blockIdx.x & 1) << 7;
  if (t0 + tloc0 >= length[b]) return;      // whole tile beyond ragged length

  __shared__ half8 As[128][5];
  __shared__ half8 Bs[128][5];

  int tid = threadIdx.x;
  int wave = tid >> 6, lane = tid & 63;
  int wm = (wave & 1) << 6, wn = (wave >> 1) << 6;
  int quad = lane >> 4, sub = lane & 15;
  int n0 = blockIdx.y << 7;

  floatx4 acc[4][4];
#pragma unroll
  for (int i = 0; i < 4; ++i)
#pragma unroll
    for (int j = 0; j < 4; ++j)
#pragma unroll
      for (int e = 0; e < 4; ++e) acc[i][j][e] = 0.f;

  size_t arowbase = (size_t)b * arst + tloc0;

  for (int kt = 0; kt < KT; ++kt) {
    int k0 = kt << 5;
#pragma unroll
    for (int pass = 0; pass < 2; ++pass) {
      int idx = tid + (pass << 8);
      int r = idx >> 2, c8 = (idx & 3) << 3;
      int kb = k0 + c8;
      half8 v;
      if (AF32) {
        const float* src = (const float*)Ab + (arowbase + r) * K + kb;
        if (kb + 8 <= K) {
          float4 u0 = *(const float4*)(src);
          float4 u1 = *(const float4*)(src + 4);
          v[0] = (_Float16)u0.x; v[1] = (_Float16)u0.y; v[2] = (_Float16)u0.z; v[3] = (_Float16)u0.w;
          v[4] = (_Float16)u1.x; v[5] = (_Float16)u1.y; v[6] = (_Float16)u1.z; v[7] = (_Float16)u1.w;
        } else {
#pragma unroll
          for (int i = 0; i < 8; ++i) v[i] = (kb + i < K) ? (_Float16)src[i] : (_Float16)0.f;
        }
      } else {
        const __half* src = (const __half*)Ab + (arowbase + r) * K + kb;
        if (kb + 8 <= K) v = *(const half8*)src;
        else {
#pragma unroll
          for (int i = 0; i < 8; ++i) v[i] = (kb + i < K) ? *(const _Float16*)(src + i) : (_Float16)0.f;
        }
      }
      As[r][c8 >> 3] = v;
      const float* bsrc = Bw + (size_t)(n0 + r) * K + kb;
      half8 w;
      if (kb + 8 <= K) {
        float4 u0 = *(const float4*)(bsrc);
        float4 u1 = *(const float4*)(bsrc + 4);
        w[0] = (_Float16)u0.x; w[1] = (_Float16)u0.y; w[2] = (_Float16)u0.z; w[3] = (_Float16)u0.w;
        w[4] = (_Float16)u1.x; w[5] = (_Float16)u1.y; w[6] = (_Float16)u1.z; w[7] = (_Float16)u1.w;
      } else {
#pragma unroll
        for (int i = 0; i < 8; ++i) w[i] = (kb + i < K) ? (_Float16)bsrc[i] : (_Float16)0.f;
      }
      Bs[r][c8 >> 3] = w;
    }
    __syncthreads();
    half8 af[4], bf[4];
#pragma unroll
    for (int i = 0; i < 4; ++i) {
      af[i] = As[wm + (i << 4) + sub][quad];
      bf[i] = Bs[wn + (i << 4) + sub][quad];
    }
#pragma unroll
    for (int mt = 0; mt < 4; ++mt)
#pragma unroll
      for (int nt = 0; nt < 4; ++nt)
        acc[mt][nt] = __builtin_amdgcn_mfma_f32_16x16x32_f16(af[mt], bf[nt], acc[mt][nt], 0, 0, 0);
    __syncthreads();
  }
  size_t mrowbase = (size_t)blockIdx.x << 7;
#pragma unroll
  for (int nt = 0; nt < 4; ++nt) {
    int n = n0 + wn + (nt << 4) + sub;
    float bv = 0.f;
    if (RELUB) bv = bias[n];
#pragma unroll
    for (int mt = 0; mt < 4; ++mt) {
#pragma unroll
      for (int r4 = 0; r4 < 4; ++r4) {
        int m = wm + (mt << 4) + (quad << 2) + r4;
        float v = acc[mt][nt][r4] + bv;
        if (RELUB) v = fmaxf(v, 0.f);
        C[(mrowbase + m) * (size_t)N + n] = __float2half(v);
      }
    }
  }
}

// ---------------- LSTM scan v2: MFMA batch-grouped.
// Group = 16 batch elems (MFMA M dim), 8 groups x 8 WGs. WG s owns h-dims
// [s*32, s*32+32) i.e. 128 gate-cols (gate-major: wave == gate). W_hh slice in
// registers as 16 B-fragments. h all-to-all within group via tagged 8B relaxed
// atomics (tag = step, parity double-buffer), staged coalesced through LDS.
__global__ __launch_bounds__(256, 2) void scan2_k(
    const __half* __restrict__ xg, const float* __restrict__ whh,
    const float* __restrict__ bih, const float* __restrict__ bhh,
    __half* __restrict__ hout, float* __restrict__ cstate,
    unsigned long long* __restrict__ exch,
    const int* __restrict__ length, int t0)
{
  const int g = blockIdx.x >> 3, s = blockIdx.x & 7;
  const int b0 = g << 4;
  int maxlen = 0;
#pragma unroll
  for (int i = 0; i < 16; ++i) maxlen = max(maxlen, length[b0 + i]);
  const int tend = min(t0 + TCH, maxlen);
  if (t0 >= tend) return;

  const int tid = threadIdx.x;
  const int wave = tid >> 6, lane = tid & 63;
  const int quad = lane >> 4, sub = lane & 15;

  __shared__ __align__(16) __half h_lds[16][264];   // [batch][dim], +8 pad
  __shared__ __align__(16) __half xgl[16][136];     // [batch][local col]
  __shared__ __align__(16) float gbuf[128][20];     // [local col][batch]

  // ---- register-resident W_hh B-fragments: B[n=gcol][k] -> lane sub = n&15
  half8 wB[8][2];
  float bias2[2];
#pragma unroll
  for (int nt = 0; nt < 2; ++nt) {
    int gcol = (wave << 8) + (s << 5) + (nt << 4) + sub;
    bias2[nt] = bih[gcol] + bhh[gcol];
#pragma unroll
    for (int kt = 0; kt < 8; ++kt) {
      const float* p = whh + (size_t)gcol * 256 + (kt << 5) + (quad << 3);
      float4 a = *(const float4*)p;
      float4 b4 = *(const float4*)(p + 4);
      half8 v;
      v[0] = (_Float16)a.x;  v[1] = (_Float16)a.y;  v[2] = (_Float16)a.z;  v[3] = (_Float16)a.w;
      v[4] = (_Float16)b4.x; v[5] = (_Float16)b4.y; v[6] = (_Float16)b4.z; v[7] = (_Float16)b4.w;
      wB[kt][nt] = v;
    }
  }

  // ---- updater identity: (batch ub, dim pair d0,d0+1)
  const int ub = tid >> 4, uc = tid & 15;
  const int d0 = uc << 1;
  float2 cc = make_float2(0.f, 0.f);
  if (t0 > 0) cc = *(const float2*)&cstate[(size_t)((b0 + ub) << 8) + (s << 5) + d0];

  if (t0 == 0) {
    unsigned* hz = (unsigned*)&h_lds[0][0];
    for (int i = tid; i < 16 * 132; i += 256) hz[i] = 0u;
  }

  // ---- staging identity: (batch sb, word-group sc of 8 tagged words)
  const int sb = tid >> 4, sc = tid & 15;
  const __half* xbase = xg + ((size_t)(b0 + sb) * TCH) * 1024
                        + ((sc >> 2) << 8) + (s << 5) + ((sc & 3) << 3);
  const unsigned long long* exrd = exch + ((size_t)(b0 + sb) << 1) * 128;
  const size_t exwr_row = ((size_t)(b0 + ub) << 1);
  const int widx = (s << 4) + uc;

  for (int t = t0; t < tend; ++t) {
    const int tl = t - t0;
    // xg prefetch (independent; latency overlaps the tag wait + MFMA)
    uint4 xv = *(const uint4*)(xbase + (size_t)tl * 1024);
    if (t > 0) {
      const unsigned long long* src = exrd + ((t & 1) << 7) + (sc << 3);
      unsigned long long w[8];
#pragma unroll
      for (int j = 0; j < 8; ++j)
        w[j] = __hip_atomic_load(src + j, __ATOMIC_RELAXED, __HIP_MEMORY_SCOPE_AGENT);
      while (true) {
        int bad = 0;
#pragma unroll
        for (int j = 0; j < 8; ++j) bad |= ((int)(unsigned)(w[j] >> 32) != t);
        if (!bad) break;
        __builtin_amdgcn_s_sleep(1);
#pragma unroll
        for (int j = 0; j < 8; ++j)
          w[j] = __hip_atomic_load(src + j, __ATOMIC_RELAXED, __HIP_MEMORY_SCOPE_AGENT);
      }
      uint4 q0, q1;
      q0.x = (unsigned)w[0]; q0.y = (unsigned)w[1]; q0.z = (unsigned)w[2]; q0.w = (unsigned)w[3];
      q1.x = (unsigned)w[4]; q1.y = (unsigned)w[5]; q1.z = (unsigned)w[6]; q1.w = (unsigned)w[7];
      *(uint4*)&h_lds[sb][(sc << 4)] = q0;
      *(uint4*)&h_lds[sb][(sc << 4) + 8] = q1;
    }
    *(uint4*)&xgl[sb][((sc >> 2) << 5) + ((sc & 3) << 3)] = xv;
    __syncthreads();

    // ---- MFMA: gates[16 batch][128 cols] += h[16][256] @ Whh_slice^T
    floatx4 acc0 = {0.f, 0.f, 0.f, 0.f}, acc1 = {0.f, 0.f, 0.f, 0.f};
#pragma unroll
    for (int kt = 0; kt < 8; ++kt) {
      half8 af = *(const half8*)&h_lds[sub][(kt << 5) + (quad << 3)];
      acc0 = __builtin_amdgcn_mfma_f32_16x16x32_f16(af, wB[kt][0], acc0, 0, 0, 0);
      acc1 = __builtin_amdgcn_mfma_f32_16x16x32_f16(af, wB[kt][1], acc1, 0, 0, 0);
    }
    // ---- epilogue: + xg + bias, nonlinearity (wave == gate), -> gbuf[n][b]
#pragma unroll
    for (int nt = 0; nt < 2; ++nt) {
      floatx4 av = nt ? acc1 : acc0;
      float4 o;
#pragma unroll
      for (int r = 0; r < 4; ++r) {
        float xvv = __half2float(xgl[(quad << 2) + r][(wave << 5) + (nt << 4) + sub]);
        float pre = av[r] + xvv + bias2[nt];
        float res;
        if (wave == 2) res = tanhf(pre);
        else           res = 1.f / (1.f + __expf(-pre));
        (&o.x)[r] = res;
      }
      *(float4*)&gbuf[(wave << 5) + (nt << 4) + sub][quad << 2] = o;
    }
    __syncthreads();

    // ---- c/h update for (ub, d0..d0+1)
    float iv0 = gbuf[d0][ub],      iv1 = gbuf[d0 + 1][ub];
    float fv0 = gbuf[32 + d0][ub], fv1 = gbuf[33 + d0][ub];
    float gv0 = gbuf[64 + d0][ub], gv1 = gbuf[65 + d0][ub];
    float ov0 = gbuf[96 + d0][ub], ov1 = gbuf[97 + d0][ub];
    cc.x = fv0 * cc.x + iv0 * gv0;
    cc.y = fv1 * cc.y + iv1 * gv1;
    float h0 = ov0 * tanhf(cc.x);
    float h1 = ov1 * tanhf(cc.y);
    unsigned pk = ((unsigned)__half_as_ushort(__float2half(h1)) << 16)
                | (unsigned)__half_as_ushort(__float2half(h0));
    *(unsigned*)&hout[(((size_t)(b0 + ub) * TCH) + tl) * 256 + (s << 5) + d0] = pk;
    __hip_atomic_store(exch + (exwr_row + ((t + 1) & 1)) * 128 + widx,
                       ((unsigned long long)(unsigned)(t + 1) << 32) | (unsigned long long)pk,
                       __ATOMIC_RELAXED, __HIP_MEMORY_SCOPE_AGENT);
    // no 3rd barrier needed: next-iter h_lds/xgl writes are gated by this
    // iter's barrier2 (all MFMA/epilogue LDS reads drained at barrier entry).
  }
  *(float2*)&cstate[(size_t)((b0 + ub) << 8) + (s << 5) + d0] = cc;
}

// ---------------- head: decision = h2 . Wd + bd, ragged-masked sum, final /len
__global__ __launch_bounds__(256, 2) void head_k(
    const __half* __restrict__ h2, const float* __restrict__ Wd,
    const float* __restrict__ bd, const int* __restrict__ length,
    float* __restrict__ dacc, float* __restrict__ out, int t0, int first, int last)
{
  int b = blockIdx.x, tid = threadIdx.x;
  int lane = tid & 63, wave = tid >> 6;
  int len = length[b];
  int tend = min(t0 + TCH, len);
  float4 w4 = *(const float4*)(Wd + (lane << 2));
  float wsum = 0.f;
  for (int t = t0 + wave; t < tend; t += 4) {
    const __half* hr = h2 + (((size_t)b * TCH) + (t - t0)) * 256 + (lane << 2);
    uint2 u = *(const uint2*)hr;
    __half2 p0 = __builtin_bit_cast(__half2, u.x);
    __half2 p1 = __builtin_bit_cast(__half2, u.y);
    float s = w4.x * __half2float(p0.x) + w4.y * __half2float(p0.y)
            + w4.z * __half2float(p1.x) + w4.w * __half2float(p1.y);
#pragma unroll
    for (int off = 32; off > 0; off >>= 1) s += __shfl_xor(s, off);
    wsum += s;
  }
  __shared__ float wred[4];
  if (lane == 0) wred[wave] = wsum;
  __syncthreads();
  if (tid == 0) {
    int cnt = tend - t0; if (cnt < 0) cnt = 0;
    float tot = wred[0] + wred[1] + wred[2] + wred[3] + bd[0] * (float)cnt;
    if (!first) tot += dacc[b];
    dacc[b] = tot;
    if (last) out[b] = tot / (float)len;
  }
}

extern "C" void kernel_launch(void* const* d_in, const int* in_sizes, int n_in,
                              void* d_out, int out_size, void* d_ws, size_t ws_size,
                              hipStream_t stream) {
  (void)in_sizes; (void)n_in; (void)out_size; (void)ws_size;
  const float* x    = (const float*)d_in[0];
  const int* length = (const int*)d_in[1];
  const float* W1   = (const float*)d_in[2];
  const float* b1   = (const float*)d_in[3];
  const float* W2   = (const float*)d_in[4];
  const float* b2   = (const float*)d_in[5];
  const float* wih[3] = {(const float*)d_in[6],  (const float*)d_in[10], (const float*)d_in[14]};
  const float* whh[3] = {(const float*)d_in[7],  (const float*)d_in[11], (const float*)d_in[15]};
  const float* bih[3] = {(const float*)d_in[8],  (const float*)d_in[12], (const float*)d_in[16]};
  const float* bhh[3] = {(const float*)d_in[9],  (const float*)d_in[13], (const float*)d_in[17]};
  const float* Wd   = (const float*)d_in[18];
  const float* bd   = (const float*)d_in[19];
  float* out = (float*)d_out;

  char* ws = (char*)d_ws;
  __half* XG    = (__half*)(ws);                     // 32768 x 1024 f16 = 64 MiB
  __half* FEAT1 = (__half*)(ws + 67108864);          // 32768 x 256  f16 = 16 MiB
  __half* FEAT2 = (__half*)(ws + 83886080);          // 32768 x 512  f16 = 32 MiB
  __half* HBUF  = (__half*)(ws + 117440512);         // 32768 x 256  f16 = 16 MiB
  unsigned long long* EXC = (unsigned long long*)(ws + 134217728);  // 3 x 32768 u64
  float* CST    = (float*)(ws + 134217728 + 786432);                // 3 x 32768 f32
  float* DACC   = (float*)(ws + 134217728 + 786432 + 393216);

  for (int c = 0; c < NCH; ++c) {
    int t0 = c * TCH;
    gemm_k<true,  true ><<<dim3(256, 2), 256, 0, stream>>>(
        (const void*)(x + (size_t)t0 * 136), W1, b1, FEAT1, length, 136, 5, 256, 1024, t0);
    gemm_k<false, true ><<<dim3(256, 4), 256, 0, stream>>>(
        (const void*)FEAT1, W2, b2, FEAT2, length, 256, 8, 512, TCH, t0);
    gemm_k<false, false><<<dim3(256, 8), 256, 0, stream>>>(
        (const void*)FEAT2, wih[0], nullptr, XG, length, 512, 16, 1024, TCH, t0);
    scan2_k<<<64, 256, 0, stream>>>(XG, whh[0], bih[0], bhh[0], HBUF,
                                    CST, EXC, length, t0);
    gemm_k<false, false><<<dim3(256, 8), 256, 0, stream>>>(
        (const void*)HBUF, wih[1], nullptr, XG, length, 256, 8, 1024, TCH, t0);
    scan2_k<<<64, 256, 0, stream>>>(XG, whh[1], bih[1], bhh[1], HBUF,
                                    CST + 32768, EXC + 32768, length, t0);
    gemm_k<false, false><<<dim3(256, 8), 256, 0, stream>>>(
        (const void*)HBUF, wih[2], nullptr, XG, length, 256, 8, 1024, TCH, t0);
    scan2_k<<<64, 256, 0, stream>>>(XG, whh[2], bih[2], bhh[2], HBUF,
                                    CST + 65536, EXC + 65536, length, t0);
    head_k<<<128, 256, 0, stream>>>(HBUF, Wd, bd, length, DACC, out, t0, c == 0, c == NCH - 1);
  }
}

// Round 3
// 8801.378 us; speedup vs baseline: 1.3416x; 1.3416x over previous
//
#include <hip/hip_runtime.h>
#include <hip/hip_fp16.h>

#define TCH 256
#define NCH 4

typedef __attribute__((ext_vector_type(8))) _Float16 half8;
typedef __attribute__((ext_vector_type(2))) _Float16 half2v;
typedef __attribute__((ext_vector_type(4))) float floatx4;

__device__ __forceinline__ float dot2f(unsigned a, unsigned b, float c) {
  return __builtin_amdgcn_fdot2(__builtin_bit_cast(half2v, a),
                                __builtin_bit_cast(half2v, b), c, false);
}
__device__ __forceinline__ float sigm_f(float x) {
  return __frcp_rn(1.f + __expf(-x));
}
__device__ __forceinline__ float tanh_f(float x) {
  return fmaf(2.f, __frcp_rn(1.f + __expf(-2.f * x)), -1.f);
}

// ---------------- GEMM: C[m,n] = A[m,:] . B[n,:]  (B row-major [N][K], fp32)
template<bool AF32, bool RELUB>
__global__ __launch_bounds__(256, 2) void gemm_k(
    const void* __restrict__ Ab, const float* __restrict__ Bw,
    const float* __restrict__ bias, __half* __restrict__ C,
    const int* __restrict__ length, int K, int KT, int N, int arst, int t0)
{
  int b = blockIdx.x >> 1;
  int tloc0 = (blockIdx.x & 1) << 7;
  if (t0 + tloc0 >= length[b]) return;

  __shared__ half8 As[128][5];
  __shared__ half8 Bs[128][5];

  int tid = threadIdx.x;
  int wave = tid >> 6, lane = tid & 63;
  int wm = (wave & 1) << 6, wn = (wave >> 1) << 6;
  int quad = lane >> 4, sub = lane & 15;
  int n0 = blockIdx.y << 7;

  floatx4 acc[4][4];
#pragma unroll
  for (int i = 0; i < 4; ++i)
#pragma unroll
    for (int j = 0; j < 4; ++j)
#pragma unroll
      for (int e = 0; e < 4; ++e) acc[i][j][e] = 0.f;

  size_t arowbase = (size_t)b * arst + tloc0;

  for (int kt = 0; kt < KT; ++kt) {
    int k0 = kt << 5;
#pragma unroll
    for (int pass = 0; pass < 2; ++pass) {
      int idx = tid + (pass << 8);
      int r = idx >> 2, c8 = (idx & 3) << 3;
      int kb = k0 + c8;
      half8 v;
      if (AF32) {
        const float* src = (const float*)Ab + (arowbase + r) * K + kb;
        if (kb + 8 <= K) {
          float4 u0 = *(const float4*)(src);
          float4 u1 = *(const float4*)(src + 4);
          v[0] = (_Float16)u0.x; v[1] = (_Float16)u0.y; v[2] = (_Float16)u0.z; v[3] = (_Float16)u0.w;
          v[4] = (_Float16)u1.x; v[5] = (_Float16)u1.y; v[6] = (_Float16)u1.z; v[7] = (_Float16)u1.w;
        } else {
#pragma unroll
          for (int i = 0; i < 8; ++i) v[i] = (kb + i < K) ? (_Float16)src[i] : (_Float16)0.f;
        }
      } else {
        const __half* src = (const __half*)Ab + (arowbase + r) * K + kb;
        if (kb + 8 <= K) v = *(const half8*)src;
        else {
#pragma unroll
          for (int i = 0; i < 8; ++i) v[i] = (kb + i < K) ? *(const _Float16*)(src + i) : (_Float16)0.f;
        }
      }
      As[r][c8 >> 3] = v;
      const float* bsrc = Bw + (size_t)(n0 + r) * K + kb;
      half8 w;
      if (kb + 8 <= K) {
        float4 u0 = *(const float4*)(bsrc);
        float4 u1 = *(const float4*)(bsrc + 4);
        w[0] = (_Float16)u0.x; w[1] = (_Float16)u0.y; w[2] = (_Float16)u0.z; w[3] = (_Float16)u0.w;
        w[4] = (_Float16)u1.x; w[5] = (_Float16)u1.y; w[6] = (_Float16)u1.z; w[7] = (_Float16)u1.w;
      } else {
#pragma unroll
        for (int i = 0; i < 8; ++i) w[i] = (kb + i < K) ? (_Float16)bsrc[i] : (_Float16)0.f;
      }
      Bs[r][c8 >> 3] = w;
    }
    __syncthreads();
    half8 af[4], bf[4];
#pragma unroll
    for (int i = 0; i < 4; ++i) {
      af[i] = As[wm + (i << 4) + sub][quad];
      bf[i] = Bs[wn + (i << 4) + sub][quad];
    }
#pragma unroll
    for (int mt = 0; mt < 4; ++mt)
#pragma unroll
      for (int nt = 0; nt < 4; ++nt)
        acc[mt][nt] = __builtin_amdgcn_mfma_f32_16x16x32_f16(af[mt], bf[nt], acc[mt][nt], 0, 0, 0);
    __syncthreads();
  }
  size_t mrowbase = (size_t)blockIdx.x << 7;
#pragma unroll
  for (int nt = 0; nt < 4; ++nt) {
    int n = n0 + wn + (nt << 4) + sub;
    float bv = 0.f;
    if (RELUB) bv = bias[n];
#pragma unroll
    for (int mt = 0; mt < 4; ++mt) {
#pragma unroll
      for (int r4 = 0; r4 < 4; ++r4) {
        int m = wm + (mt << 4) + (quad << 2) + r4;
        float v = acc[mt][nt][r4] + bv;
        if (RELUB) v = fmaxf(v, 0.f);
        C[(mrowbase + m) * (size_t)N + n] = __float2half(v);
      }
    }
  }
}

// ---------------- weight prep: pack whh f32 -> f16 pairs, [layer][row][128 pairs]
__global__ __launch_bounds__(256, 4) void prep_k(
    const float* __restrict__ w0, const float* __restrict__ w1,
    const float* __restrict__ w2, unsigned* __restrict__ wpk)
{
  int g = blockIdx.x * 256 + threadIdx.x;      // 3*131072 total
  int l = g >> 17, rem = g & 131071;
  const float* src = (l == 0) ? w0 : (l == 1) ? w1 : w2;
  float2 f = *(const float2*)(src + ((size_t)rem << 1));
  wpk[g] = ((unsigned)__half_as_ushort(__float2half(f.y)) << 16)
         | (unsigned)__half_as_ushort(__float2half(f.x));
}

// ---------------- LSTM scan v3: single WG per batch element. 512 threads.
// Thread t owns gate-rows t and t+512 (one shared readlane stream for both).
// W_hh: K[0,192) in 192 VGPRs (96 pairs x 2 rows), K[192,256) in LDS
// (XOR-swizzled, 128 KB). h exchange purely via LDS + barriers. No atomics.
__global__ __launch_bounds__(512, 2) void scan3_k(
    const __half* __restrict__ xg, const unsigned* __restrict__ wpk,
    const float* __restrict__ bih, const float* __restrict__ bhh,
    __half* __restrict__ hout, unsigned* __restrict__ hstate,
    float* __restrict__ cstate, const int* __restrict__ length, int t0)
{
  extern __shared__ char smem[];
  unsigned* WL = (unsigned*)smem;                      // [1024][32] swizzled pairs
  float* gbuf  = (float*)(smem + 131072);              // [1024]
  __half* hh   = (__half*)(smem + 131072 + 4096);      // [256]

  const int b = blockIdx.x;
  const int len = length[b];
  const int tend = min(t0 + TCH, len);
  if (t0 >= tend) return;

  const int tid = threadIdx.x;
  const int lane = tid & 63;
  const int r0 = tid, r1 = tid + 512;

  // ---- preamble: load packed weights
  unsigned w0[96], w1[96];
  {
    const uint4* p0 = (const uint4*)(wpk + ((size_t)r0 << 7));
    const uint4* p1 = (const uint4*)(wpk + ((size_t)r1 << 7));
#pragma unroll
    for (int i = 0; i < 24; ++i) {
      uint4 a = p0[i];
      w0[4*i] = a.x; w0[4*i+1] = a.y; w0[4*i+2] = a.z; w0[4*i+3] = a.w;
      uint4 c = p1[i];
      w1[4*i] = c.x; w1[4*i+1] = c.y; w1[4*i+2] = c.z; w1[4*i+3] = c.w;
    }
#pragma unroll
    for (int c = 0; c < 8; ++c) {
      uint4 a = p0[24 + c];
      *(uint4*)&WL[(r0 << 5) + ((c ^ (r0 & 7)) << 2)] = a;
      uint4 d = p1[24 + c];
      *(uint4*)&WL[(r1 << 5) + ((c ^ (r1 & 7)) << 2)] = d;
    }
  }
  const float bias0 = bih[r0] + bhh[r0];
  const float bias1 = bih[r1] + bhh[r1];

  unsigned hp0 = 0, hp1 = 0;
  float cv = 0.f;
  if (t0 > 0) {
    hp0 = hstate[(b << 7) + lane];
    hp1 = hstate[(b << 7) + 64 + lane];
    if (tid < 256) cv = cstate[(b << 8) + tid];
  }
  __syncthreads();   // WL ready

  const __half* xgb = xg + (((size_t)b * TCH) << 10) + tid;
  float xv0 = __half2float(xgb[0]);
  float xv1 = __half2float(xgb[512]);

  for (int t = t0; t < tend; ++t) {
    const int tl = t - t0;
    // prefetch next step's xg (latency hidden by dot loop)
    const int tln = min(tl + 1, TCH - 1);
    __half nx0 = xgb[(size_t)tln << 10];
    __half nx1 = xgb[((size_t)tln << 10) + 512];

    float a00 = 0.f, a01 = 0.f, a10 = 0.f, a11 = 0.f;
    // software-pipelined LDS weight chunks (2 ahead) interleaved with reg pairs
    uint4 q0[2], q1[2];
    q0[0] = *(const uint4*)&WL[(r0 << 5) + ((0 ^ (r0 & 7)) << 2)];
    q1[0] = *(const uint4*)&WL[(r1 << 5) + ((0 ^ (r1 & 7)) << 2)];
    q0[1] = *(const uint4*)&WL[(r0 << 5) + ((1 ^ (r0 & 7)) << 2)];
    q1[1] = *(const uint4*)&WL[(r1 << 5) + ((1 ^ (r1 & 7)) << 2)];
#pragma unroll
    for (int s = 0; s < 8; ++s) {
#pragma unroll
      for (int j = 0; j < 12; ++j) {
        const int p = s * 12 + j;
        unsigned rl = (unsigned)__builtin_amdgcn_readlane(
            (p < 64) ? (int)hp0 : (int)hp1, p & 63);
        if (j & 1) { a01 = dot2f(w0[p], rl, a01); a11 = dot2f(w1[p], rl, a11); }
        else       { a00 = dot2f(w0[p], rl, a00); a10 = dot2f(w1[p], rl, a10); }
      }
      uint4 c0 = q0[s & 1], c1 = q1[s & 1];
      if (s < 6) {
        q0[s & 1] = *(const uint4*)&WL[(r0 << 5) + (((s + 2) ^ (r0 & 7)) << 2)];
        q1[s & 1] = *(const uint4*)&WL[(r1 << 5) + (((s + 2) ^ (r1 & 7)) << 2)];
      }
#pragma unroll
      for (int j = 0; j < 4; ++j) {
        unsigned rl = (unsigned)__builtin_amdgcn_readlane((int)hp1, 32 + s * 4 + j);
        a01 = dot2f((&c0.x)[j], rl, a01);
        a11 = dot2f((&c1.x)[j], rl, a11);
      }
    }
    float pre0 = a00 + a01 + xv0 + bias0;
    float pre1 = a10 + a11 + xv1 + bias1;
    // r0: i (tid<256) or f -> sigmoid. r1: g (tid<256, tanh) or o (sigmoid).
    float g0 = sigm_f(pre0);
    float g1 = (tid < 256) ? tanh_f(pre1) : sigm_f(pre1);
    gbuf[r0] = g0;
    gbuf[r1] = g1;
    __syncthreads();
    if (tid < 256) {
      float iv = gbuf[tid], fv = gbuf[256 + tid];
      float gv = gbuf[512 + tid], ov = gbuf[768 + tid];
      cv = fv * cv + iv * gv;
      float hv = ov * tanh_f(cv);
      __half hx = __float2half(hv);
      hh[tid] = hx;
      hout[(((size_t)b * TCH) + tl) * 256 + tid] = hx;
    }
    __syncthreads();
    hp0 = ((const unsigned*)hh)[lane];
    hp1 = ((const unsigned*)hh)[64 + lane];
    xv0 = __half2float(nx0);
    xv1 = __half2float(nx1);
  }
  if (tid < 64)       hstate[(b << 7) + tid] = hp0;
  else if (tid < 128) hstate[(b << 7) + tid] = hp1;
  if (tid < 256) cstate[(b << 8) + tid] = cv;
}

// ---------------- head: decision = h2 . Wd + bd, ragged-masked sum, final /len
__global__ __launch_bounds__(256, 2) void head_k(
    const __half* __restrict__ h2, const float* __restrict__ Wd,
    const float* __restrict__ bd, const int* __restrict__ length,
    float* __restrict__ dacc, float* __restrict__ out, int t0, int first, int last)
{
  int b = blockIdx.x, tid = threadIdx.x;
  int lane = tid & 63, wave = tid >> 6;
  int len = length[b];
  int tend = min(t0 + TCH, len);
  float4 w4 = *(const float4*)(Wd + (lane << 2));
  float wsum = 0.f;
  for (int t = t0 + wave; t < tend; t += 4) {
    const __half* hr = h2 + (((size_t)b * TCH) + (t - t0)) * 256 + (lane << 2);
    uint2 u = *(const uint2*)hr;
    __half2 p0 = __builtin_bit_cast(__half2, u.x);
    __half2 p1 = __builtin_bit_cast(__half2, u.y);
    float s = w4.x * __half2float(p0.x) + w4.y * __half2float(p0.y)
            + w4.z * __half2float(p1.x) + w4.w * __half2float(p1.y);
#pragma unroll
    for (int off = 32; off > 0; off >>= 1) s += __shfl_xor(s, off);
    wsum += s;
  }
  __shared__ float wred[4];
  if (lane == 0) wred[wave] = wsum;
  __syncthreads();
  if (tid == 0) {
    int cnt = tend - t0; if (cnt < 0) cnt = 0;
    float tot = wred[0] + wred[1] + wred[2] + wred[3] + bd[0] * (float)cnt;
    if (!first) tot += dacc[b];
    dacc[b] = tot;
    if (last) out[b] = tot / (float)len;
  }
}

extern "C" void kernel_launch(void* const* d_in, const int* in_sizes, int n_in,
                              void* d_out, int out_size, void* d_ws, size_t ws_size,
                              hipStream_t stream) {
  (void)in_sizes; (void)n_in; (void)out_size; (void)ws_size;
  const float* x    = (const float*)d_in[0];
  const int* length = (const int*)d_in[1];
  const float* W1   = (const float*)d_in[2];
  const float* b1   = (const float*)d_in[3];
  const float* W2   = (const float*)d_in[4];
  const float* b2   = (const float*)d_in[5];
  const float* wih[3] = {(const float*)d_in[6],  (const float*)d_in[10], (const float*)d_in[14]};
  const float* whh[3] = {(const float*)d_in[7],  (const float*)d_in[11], (const float*)d_in[15]};
  const float* bih[3] = {(const float*)d_in[8],  (const float*)d_in[12], (const float*)d_in[16]};
  const float* bhh[3] = {(const float*)d_in[9],  (const float*)d_in[13], (const float*)d_in[17]};
  const float* Wd   = (const float*)d_in[18];
  const float* bd   = (const float*)d_in[19];
  float* out = (float*)d_out;

  char* ws = (char*)d_ws;
  __half* XG    = (__half*)(ws);                     // 32768 x 1024 f16 = 64 MiB
  __half* FEAT1 = (__half*)(ws + 67108864);          // 32768 x 256  f16 = 16 MiB
  __half* FEAT2 = (__half*)(ws + 83886080);          // 32768 x 512  f16 = 32 MiB
  __half* HBUF  = (__half*)(ws + 117440512);         // 32768 x 256  f16 = 16 MiB
  unsigned* WPK = (unsigned*)(ws + 134217728);               // 3 x 131072 u32 = 1.5 MiB
  float* CST    = (float*)(ws + 134217728 + 1572864);        // 3 x 32768 f32
  unsigned* HST = (unsigned*)(ws + 134217728 + 1572864 + 393216);  // 3 x 16384 u32
  float* DACC   = (float*)(ws + 134217728 + 1572864 + 393216 + 196608);

  (void)hipFuncSetAttribute((const void*)scan3_k,
      hipFuncAttributeMaxDynamicSharedMemorySize, 136192);
  const int SMEM = 131072 + 4096 + 512;

  prep_k<<<1536, 256, 0, stream>>>(whh[0], whh[1], whh[2], WPK);

  for (int c = 0; c < NCH; ++c) {
    int t0 = c * TCH;
    gemm_k<true,  true ><<<dim3(256, 2), 256, 0, stream>>>(
        (const void*)(x + (size_t)t0 * 136), W1, b1, FEAT1, length, 136, 5, 256, 1024, t0);
    gemm_k<false, true ><<<dim3(256, 4), 256, 0, stream>>>(
        (const void*)FEAT1, W2, b2, FEAT2, length, 256, 8, 512, TCH, t0);
    gemm_k<false, false><<<dim3(256, 8), 256, 0, stream>>>(
        (const void*)FEAT2, wih[0], nullptr, XG, length, 512, 16, 1024, TCH, t0);
    scan3_k<<<128, 512, SMEM, stream>>>(XG, WPK, bih[0], bhh[0], HBUF,
                                        HST, CST, length, t0);
    gemm_k<false, false><<<dim3(256, 8), 256, 0, stream>>>(
        (const void*)HBUF, wih[1], nullptr, XG, length, 256, 8, 1024, TCH, t0);
    scan3_k<<<128, 512, SMEM, stream>>>(XG, WPK + 131072, bih[1], bhh[1], HBUF,
                                        HST + 16384, CST + 32768, length, t0);
    gemm_k<false, false><<<dim3(256, 8), 256, 0, stream>>>(
        (const void*)HBUF, wih[2], nullptr, XG, length, 256, 8, 1024, TCH, t0);
    scan3_k<<<128, 512, SMEM, stream>>>(XG, WPK + 262144, bih[2], bhh[2], HBUF,
                                        HST + 32768, CST + 65536, length, t0);
    head_k<<<128, 256, 0, stream>>>(HBUF, Wd, bd, length, DACC, out, t0, c == 0, c == NCH - 1);
  }
}